// Round 3
// baseline (214.956 us; speedup 1.0000x reference)
//
#include <hip/hip_runtime.h>

// YOLO loss: pred/target (4096, 30, 14, 14) f32 -> scalar. Memory-bound.
// R3: one block per image. Box planes (d=0..9, both tensors) staged to LDS via
// contiguous float4 loads; class planes (d=10..29, 2/3 of bytes) streamed
// directly with contiguous float4 loads issued before the barrier.
// R1/R2 were stuck at ~1.4 TB/s: per-thread plane-strided loads (784 B stride)
// gave the compiler too few outstanding loads per wave. All loads are now
// copy-kernel-shaped.

#define S_GRID 14
#define SS 196            // S*S
#define N_BATCH 4096
#define LAMBDA_COORD 5.0f
#define LAMBDA_NOOBJ 0.5f
// per image: 30 planes * 196 = 5880 floats; box chunk = 10*196 = 1960 floats
//   = 490 float4; class chunk = 20*196 = 3920 floats = 980 float4.

__global__ __launch_bounds__(256) void yolo_loss_kernel(
    const float* __restrict__ pred,
    const float* __restrict__ tgt,
    float* __restrict__ out)
{
    const int n   = blockIdx.x;
    const int tid = threadIdx.x;

    // LDS: pred box planes [0..1959], tgt box planes [1960..3919]
    __shared__ __align__(16) float sb[3920];

    const float4* pb4 = (const float4*)(pred + (size_t)n * 5880);  // 490 box quads
    const float4* tb4 = (const float4*)(tgt  + (size_t)n * 5880);
    const float4* pc4 = pb4 + 490;   // 980 class quads
    const float4* tc4 = tb4 + 490;
    float4* sb4 = (float4*)sb;

    // ---- stage box planes to LDS (contiguous) ----
#pragma unroll
    for (int k = 0; k < 2; ++k) {
        int i = tid + k * 256;
        if (i < 490) sb4[i] = pb4[i];
    }
#pragma unroll
    for (int k = 0; k < 2; ++k) {
        int i = tid + k * 256;
        if (i < 490) sb4[490 + i] = tb4[i];
    }

    // ---- issue class-plane loads now (independent of LDS/barrier) ----
    float4 cp[4], ct[4];
#pragma unroll
    for (int k = 0; k < 4; ++k) {
        int i = tid + k * 256;
        if (i < 980) { cp[k] = pc4[i]; ct[k] = tc4[i]; }
    }

    __syncthreads();   // staging visible (drains vmcnt + lds writes)

    // ---- class term: obj[cell] * (p - t)^2, mask from staged tgt conf plane ----
    float total = 0.f;
#pragma unroll
    for (int k = 0; k < 4; ++k) {
        int i = tid + k * 256;
        if (i < 980) {
            int cell0 = (i % 49) * 4;          // quad within its plane -> base cell
            const float* objp = &sb[1960 + 4 * SS + cell0];
            float4 p = cp[k], t = ct[k];
            float d0 = p.x - t.x, d1 = p.y - t.y, d2 = p.z - t.z, d3 = p.w - t.w;
            float a0 = (objp[0] > 0.f) ? d0 * d0 : 0.f;
            float a1 = (objp[1] > 0.f) ? d1 * d1 : 0.f;
            float a2 = (objp[2] > 0.f) ? d2 * d2 : 0.f;
            float a3 = (objp[3] > 0.f) ? d3 * d3 : 0.f;
            total += (a0 + a1) + (a2 + a3);
        }
    }

    // ---- box/conf terms: one cell per thread (tid < 196) ----
    if (tid < SS) {
        const int c = tid;
        float P[10], T[10];
#pragma unroll
        for (int d = 0; d < 10; ++d) {
            P[d] = sb[d * SS + c];
            T[d] = sb[1960 + d * SS + c];
        }

        const float tconf = T[4];
        const float obj   = (tconf > 0.f)  ? 1.f : 0.f;
        const float noobj = (tconf == 0.f) ? 1.f : 0.f;

        const float dc0 = P[4] - T[4];
        const float dc1 = P[9] - T[9];
        const float noobj_term = noobj * (dc0 * dc0 + dc1 * dc1);

        const float tcx = T[0] * (1.f / S_GRID);
        const float tcy = T[1] * (1.f / S_GRID);
        const float tltx = tcx - 0.5f * T[2], trbx = tcx + 0.5f * T[2];
        const float tlty = tcy - 0.5f * T[3], trby = tcy + 0.5f * T[3];
        const float tarea = (trbx - tltx) * (trby - tlty);

        float iou0 = 0.f, iou1 = 0.f;
#pragma unroll
        for (int b = 0; b < 2; ++b) {
            const int o = 5 * b;
            const float pcx = P[o + 0] * (1.f / S_GRID);
            const float pcy = P[o + 1] * (1.f / S_GRID);
            const float pltx = pcx - 0.5f * P[o + 2], prbx = pcx + 0.5f * P[o + 2];
            const float plty = pcy - 0.5f * P[o + 3], prby = pcy + 0.5f * P[o + 3];
            const float ltx = fmaxf(tltx, pltx), rbx = fminf(trbx, prbx);
            const float lty = fmaxf(tlty, plty), rby = fminf(trby, prby);
            const float w = fmaxf(rbx - ltx, 0.f), h = fmaxf(rby - lty, 0.f);
            const float inter = w * h;
            const float parea = (prbx - pltx) * (prby - plty);
            const float uni = tarea + parea - inter;
            const float iou = inter / ((uni == 0.f) ? 1.f : uni);
            if (b == 0) iou0 = iou; else iou1 = iou;
        }

        const bool r = (iou1 > iou0);           // jnp.argmax: first max on tie
        const float miou = fmaxf(iou0, iou1);

        const float bpr0 = r ? P[5] : P[0];
        const float bpr1 = r ? P[6] : P[1];
        const float bpr2 = r ? P[7] : P[2];
        const float bpr3 = r ? P[8] : P[3];
        const float bpr4 = r ? P[9] : P[4];
        const float btr0 = r ? T[5] : T[0];
        const float btr1 = r ? T[6] : T[1];
        const float btr2 = r ? T[7] : T[2];
        const float btr3 = r ? T[8] : T[3];

        const float dx = bpr0 - btr0, dy = bpr1 - btr1;
        const float dw = bpr2 - btr2, dh = bpr3 - btr3;
        const float dxy = dx * dx + dy * dy;
        const float dwh = dw * dw + dh * dh;
        const float dconf = bpr4 - miou;

        total += obj * (LAMBDA_COORD * (dxy + dwh) + dconf * dconf)
               + LAMBDA_NOOBJ * noobj_term;
    }

    // ---- reduce: wave(64) shuffle -> LDS -> one atomic per block ----
#pragma unroll
    for (int off = 32; off > 0; off >>= 1)
        total += __shfl_down(total, off);

    __shared__ float wsum[4];
    const int wid  = tid >> 6;
    const int lane = tid & 63;
    if (lane == 0) wsum[wid] = total;
    __syncthreads();
    if (tid == 0) {
        float s = wsum[0] + wsum[1] + wsum[2] + wsum[3];
        atomicAdd(out, s * (1.0f / N_BATCH));
    }
}

extern "C" void kernel_launch(void* const* d_in, const int* in_sizes, int n_in,
                              void* d_out, int out_size, void* d_ws, size_t ws_size,
                              hipStream_t stream) {
    const float* pred = (const float*)d_in[0];
    const float* tgt  = (const float*)d_in[1];
    float* out = (float*)d_out;

    // d_out is re-poisoned (0xAA) before every timed replay; zero it ourselves.
    hipMemsetAsync(out, 0, sizeof(float), stream);

    hipLaunchKernelGGL(yolo_loss_kernel, dim3(N_BATCH), dim3(256), 0, stream,
                       pred, tgt, out);
}

// Round 4
// 202.317 us; speedup vs baseline: 1.0625x; 1.0625x over previous
//
#include <hip/hip_runtime.h>

// YOLO loss: pred/target (4096, 30, 14, 14) f32 -> scalar. Memory-bound.
// R4: R1-R3 all plateaued at ~2.5 TB/s total-byte rate with VGPR_Count 24-76:
// compiler recycles load-dest registers -> vmcnt waits every few loads ->
// per-wave MLP ~3. Fix: stage box planes via global_load_lds (width 16,
// zero VGPR cost, no intermediate waitcnt), stream class planes into
// registers, first drain only at the barrier. Box LDS regions padded to
// 512 quads so staging masks are full-wave (global_load_lds dest is
// wave-uniform base + lane*16 -- safe only with prefix-active lanes).
// Per-block partial sums -> d_ws (plain store), tiny reduce kernel sums.

#define S_GRID 14
#define SS 196            // S*S
#define N_BATCH 4096
#define LAMBDA_COORD 5.0f
#define LAMBDA_NOOBJ 0.5f
// per image: 30 planes * 196 = 5880 floats = 1470 quads;
// box chunk = 490 quads (staged, padded to 512); class chunk = 980 quads.

#define GLOAD_LDS16(g, l)                                              \
    __builtin_amdgcn_global_load_lds(                                  \
        (const __attribute__((address_space(1))) void*)(g),            \
        (__attribute__((address_space(3))) void*)(l), 16, 0, 0)

__global__ __launch_bounds__(256) void yolo_loss_kernel(
    const float* __restrict__ pred,
    const float* __restrict__ tgt,
    float* __restrict__ part)
{
    const int n   = blockIdx.x;
    const int tid = threadIdx.x;

    // LDS: pred box planes at sb[0..1959] (pad to 2048), tgt box planes at
    // sb[2048..4007] (pad region holds junk class data, never read).
    __shared__ __align__(16) float sb[4096];
    __shared__ float wsum[4];

    const float4* pb4 = (const float4*)(pred + (size_t)n * 5880);
    const float4* tb4 = (const float4*)(tgt  + (size_t)n * 5880);

    // ---- stage box planes (+pad) to LDS via direct global->LDS DMA ----
    // 512 quads per tensor, 256 threads -> 2 iters, full-wave, no masks.
#pragma unroll
    for (int k = 0; k < 2; ++k) {
        const int i = tid + k * 256;
        GLOAD_LDS16(pb4 + i, sb + 4 * i);
        GLOAD_LDS16(tb4 + i, sb + 2048 + 4 * i);
    }

    // ---- class-plane register loads (independent, fly during staging) ----
    const float4* pc4 = pb4 + 490;
    const float4* tc4 = tb4 + 490;
    float4 cp[4], ct[4];
#pragma unroll
    for (int k = 0; k < 4; ++k) {
        const int i = tid + k * 256;
        if (i < 980) { cp[k] = pc4[i]; ct[k] = tc4[i]; }
    }

    __syncthreads();   // drains vmcnt(0): staging + class loads complete

    // ---- class term: obj[cell] * (p - t)^2, mask from staged tgt conf ----
    float total = 0.f;
#pragma unroll
    for (int k = 0; k < 4; ++k) {
        const int i = tid + k * 256;
        if (i < 980) {
            const int cell0 = (i % 49) * 4;          // quad -> base cell in plane
            const float* objp = &sb[2048 + 4 * SS + cell0];
            const float4 p = cp[k], t = ct[k];
            const float d0 = p.x - t.x, d1 = p.y - t.y;
            const float d2 = p.z - t.z, d3 = p.w - t.w;
            const float a0 = (objp[0] > 0.f) ? d0 * d0 : 0.f;
            const float a1 = (objp[1] > 0.f) ? d1 * d1 : 0.f;
            const float a2 = (objp[2] > 0.f) ? d2 * d2 : 0.f;
            const float a3 = (objp[3] > 0.f) ? d3 * d3 : 0.f;
            total += (a0 + a1) + (a2 + a3);
        }
    }

    // ---- box/conf terms: one cell per thread (tid < 196) ----
    if (tid < SS) {
        const int c = tid;
        float P[10], T[10];
#pragma unroll
        for (int d = 0; d < 10; ++d) {
            P[d] = sb[d * SS + c];
            T[d] = sb[2048 + d * SS + c];
        }

        const float tconf = T[4];
        const float obj   = (tconf > 0.f)  ? 1.f : 0.f;
        const float noobj = (tconf == 0.f) ? 1.f : 0.f;

        const float dc0 = P[4] - T[4];
        const float dc1 = P[9] - T[9];
        const float noobj_term = noobj * (dc0 * dc0 + dc1 * dc1);

        const float tcx = T[0] * (1.f / S_GRID);
        const float tcy = T[1] * (1.f / S_GRID);
        const float tltx = tcx - 0.5f * T[2], trbx = tcx + 0.5f * T[2];
        const float tlty = tcy - 0.5f * T[3], trby = tcy + 0.5f * T[3];
        const float tarea = (trbx - tltx) * (trby - tlty);

        float iou0 = 0.f, iou1 = 0.f;
#pragma unroll
        for (int b = 0; b < 2; ++b) {
            const int o = 5 * b;
            const float pcx = P[o + 0] * (1.f / S_GRID);
            const float pcy = P[o + 1] * (1.f / S_GRID);
            const float pltx = pcx - 0.5f * P[o + 2], prbx = pcx + 0.5f * P[o + 2];
            const float plty = pcy - 0.5f * P[o + 3], prby = pcy + 0.5f * P[o + 3];
            const float ltx = fmaxf(tltx, pltx), rbx = fminf(trbx, prbx);
            const float lty = fmaxf(tlty, plty), rby = fminf(trby, prby);
            const float w = fmaxf(rbx - ltx, 0.f), h = fmaxf(rby - lty, 0.f);
            const float inter = w * h;
            const float parea = (prbx - pltx) * (prby - plty);
            const float uni = tarea + parea - inter;
            const float iou = inter / ((uni == 0.f) ? 1.f : uni);
            if (b == 0) iou0 = iou; else iou1 = iou;
        }

        const bool r = (iou1 > iou0);           // jnp.argmax: first max on tie
        const float miou = fmaxf(iou0, iou1);

        const float bpr0 = r ? P[5] : P[0];
        const float bpr1 = r ? P[6] : P[1];
        const float bpr2 = r ? P[7] : P[2];
        const float bpr3 = r ? P[8] : P[3];
        const float bpr4 = r ? P[9] : P[4];
        const float btr0 = r ? T[5] : T[0];
        const float btr1 = r ? T[6] : T[1];
        const float btr2 = r ? T[7] : T[2];
        const float btr3 = r ? T[8] : T[3];

        const float dx = bpr0 - btr0, dy = bpr1 - btr1;
        const float dw = bpr2 - btr2, dh = bpr3 - btr3;
        const float dxy = dx * dx + dy * dy;
        const float dwh = dw * dw + dh * dh;
        const float dconf = bpr4 - miou;

        total += obj * (LAMBDA_COORD * (dxy + dwh) + dconf * dconf)
               + LAMBDA_NOOBJ * noobj_term;
    }

    // ---- reduce: wave(64) shuffle -> LDS -> one plain store per block ----
#pragma unroll
    for (int off = 32; off > 0; off >>= 1)
        total += __shfl_down(total, off);

    const int wid  = tid >> 6;
    const int lane = tid & 63;
    if (lane == 0) wsum[wid] = total;
    __syncthreads();
    if (tid == 0)
        part[n] = (wsum[0] + wsum[1]) + (wsum[2] + wsum[3]);
}

__global__ __launch_bounds__(256) void reduce_kernel(
    const float* __restrict__ part, float* __restrict__ out)
{
    const int tid = threadIdx.x;
    float s = 0.f;
#pragma unroll
    for (int k = 0; k < 16; ++k)
        s += part[tid + k * 256];
#pragma unroll
    for (int off = 32; off > 0; off >>= 1)
        s += __shfl_down(s, off);
    __shared__ float w[4];
    if ((tid & 63) == 0) w[tid >> 6] = s;
    __syncthreads();
    if (tid == 0)
        out[0] = ((w[0] + w[1]) + (w[2] + w[3])) * (1.0f / N_BATCH);
}

extern "C" void kernel_launch(void* const* d_in, const int* in_sizes, int n_in,
                              void* d_out, int out_size, void* d_ws, size_t ws_size,
                              hipStream_t stream) {
    const float* pred = (const float*)d_in[0];
    const float* tgt  = (const float*)d_in[1];
    float* out  = (float*)d_out;
    float* part = (float*)d_ws;     // 4096 floats of scratch

    hipLaunchKernelGGL(yolo_loss_kernel, dim3(N_BATCH), dim3(256), 0, stream,
                       pred, tgt, part);
    hipLaunchKernelGGL(reduce_kernel, dim3(1), dim3(256), 0, stream,
                       part, out);
}